// Round 4
// baseline (525618.408 us; speedup 1.0000x reference)
//
#include <hip/hip_runtime.h>

// ContinuousGRULayer round 4: weights VGPR-resident, output-split across WGs,
// flag-barrier h/rh exchange.
//   Grid = 128 WGs x 1024 thr = 16 chain-groups x 8 WGs. WG (cg,n) owns
//   neurons [n*64, n*64+64) for chains [cg*8, cg*8+8).
//   Recurrent weights: each thread holds f16-packed K-slices in registers
//   (wA: z|r gate, K=64 slice; wB: g gate, K=64 slice) -> dots read weights
//   for free; h/rh broadcast from LDS (wave-uniform ds reads).
//   Cross-WG exchange per chain-group via d_ws + epoch-counter barriers
//   (8 participants, device-scope atomics + __threadfence for XCD coherence).

namespace {
constexpr int kB = 128, kT = 512, kF = 128, kH = 512, kFH = 640;
constexpr int NG = 16;    // chain groups
constexpr int WPG = 8;    // WGs per group
constexpr int MC = 8;     // chains per group
constexpr int NJ = 64;    // neurons per WG
// d_ws layout (bytes)
constexpr size_t HX_BYTES = (size_t)NG * MC * kH * 2;   // 128 KB h exchange
constexpr size_t HX_OFF  = 0;
constexpr size_t RHX_OFF = HX_OFF + HX_BYTES;           // 128 KB rh exchange
constexpr size_t CTR_OFF = RHX_OFF + HX_BYTES;          // 16 ctrs, 64B apart
}  // namespace

typedef _Float16 h2_t __attribute__((ext_vector_type(2)));

__device__ __forceinline__ unsigned short f2h(float f) {
  return __builtin_bit_cast(unsigned short, (_Float16)f);
}
__device__ __forceinline__ unsigned pack2h(float a, float b) {
  return (unsigned)f2h(a) | ((unsigned)f2h(b) << 16);
}
__device__ __forceinline__ float dot2(unsigned w, unsigned h, float acc) {
  return __builtin_amdgcn_fdot2(__builtin_bit_cast(h2_t, w),
                                __builtin_bit_cast(h2_t, h), acc, false);
}
__device__ __forceinline__ float dot2x4(uint4 w, uint4 h, float acc) {
  acc = dot2(w.x, h.x, acc); acc = dot2(w.y, h.y, acc);
  acc = dot2(w.z, h.z, acc); acc = dot2(w.w, h.w, acc);
  return acc;
}

__global__ void init_ws(unsigned* ws_u) {
  const unsigned i = blockIdx.x * 256 + threadIdx.x;
  if (i < HX_BYTES / 4) ws_u[HX_OFF / 4 + i] = 0;       // h exchange = 0
  if (i < 256) ws_u[CTR_OFF / 4 + i] = 0;               // barrier counters
}

__device__ __forceinline__ void bar_arrive(unsigned* c) {
  __threadfence();          // drain this thread's stores; L2 writeback
  __syncthreads();          // all threads' fences done
  if (threadIdx.x == 0) atomicAdd(c, 1u);
}
__device__ __forceinline__ void bar_wait(unsigned* c, unsigned target) {
  if (threadIdx.x == 0) {
    while (__hip_atomic_load(c, __ATOMIC_RELAXED, __HIP_MEMORY_SCOPE_AGENT) <
           target) {
      __builtin_amdgcn_s_sleep(1);
    }
  }
  __syncthreads();
  __threadfence();          // invalidate L1/L2 before reading exchanged data
}

__global__ __launch_bounds__(1024, 1) void cgru_coop(
    const float* __restrict__ x, const float* __restrict__ td,
    const float* __restrict__ Wz, const float* __restrict__ bz,
    const float* __restrict__ Wr, const float* __restrict__ br,
    const float* __restrict__ Wg, const float* __restrict__ bg,
    void* __restrict__ ws, float* __restrict__ out) {
  __shared__ __align__(16) uint4 WxL[3][16][NJ];      // 48 KB x-part weights
  __shared__ __align__(16) uint4 hb4[MC * kH / 8];    // 8 KB  h / rh buffer
  __shared__ __align__(16) unsigned xbs[MC * kF / 2]; // 2 KB  x_t f16-packed
  __shared__ float partA[2][8][MC][NJ];               // 32 KB z/r partials
  __shared__ float partB[8][MC][NJ];                  // 16 KB g partials

  const int wg = blockIdx.x;
  const int cg = wg >> 3;          // chain group
  const int n  = wg & 7;           // neuron group
  const int tid = threadIdx.x;
  const int jj = tid & 63;
  const int j  = n * NJ + jj;      // global neuron
  // phase A role: (jj, gate, ksA)
  const int gA  = (tid >> 6) & 1;
  const int ksA = tid >> 7;        // 0..7  (K-slice of 64)
  // phase B role: (jj, ksB, mgB)
  const int ksB = (tid >> 6) & 7;
  const int mgB = tid >> 9;        // 0..1  (4 chains each)
  // state role (tid < 512): (sm, jj)
  const int sm = tid >> 6;

  unsigned short* hx =
      (unsigned short*)((char*)ws + HX_OFF) + (size_t)cg * MC * kH;
  unsigned short* rhx =
      (unsigned short*)((char*)ws + RHX_OFF) + (size_t)cg * MC * kH;
  const uint4* hx4  = (const uint4*)hx;
  const uint4* rhx4 = (const uint4*)rhx;
  unsigned* ctr = (unsigned*)((char*)ws + CTR_OFF + (size_t)cg * 64);

  // ---- recurrent weight slices -> registers (f16 k8-packed) ----
  uint4 wA[8], wB[8];
  {
    const float* rowA = (gA ? Wr : Wz) + (size_t)j * kFH + kF + ksA * 64;
    const float* rowB = Wg + (size_t)j * kFH + kF + ksB * 64;
#pragma unroll
    for (int p = 0; p < 8; ++p) {
      float4 a = *(const float4*)(rowA + p * 8);
      float4 b = *(const float4*)(rowA + p * 8 + 4);
      wA[p].x = pack2h(a.x, a.y); wA[p].y = pack2h(a.z, a.w);
      wA[p].z = pack2h(b.x, b.y); wA[p].w = pack2h(b.z, b.w);
      float4 c = *(const float4*)(rowB + p * 8);
      float4 d = *(const float4*)(rowB + p * 8 + 4);
      wB[p].x = pack2h(c.x, c.y); wB[p].y = pack2h(c.z, c.w);
      wB[p].z = pack2h(d.x, d.y); wB[p].w = pack2h(d.z, d.w);
    }
  }
  // ---- x-part weights -> LDS (once) ----
  for (int q = tid; q < 3 * 16 * NJ; q += 1024) {
    const int gate = q >> 10, rem = q & 1023, p = rem >> 6, jw = rem & 63;
    const float* W = (gate == 0) ? Wz : (gate == 1) ? Wr : Wg;
    const float* s = W + (size_t)(n * NJ + jw) * kFH + p * 8;
    float4 a = *(const float4*)s;
    float4 b = *(const float4*)(s + 4);
    uint4 o;
    o.x = pack2h(a.x, a.y); o.y = pack2h(a.z, a.w);
    o.z = pack2h(b.x, b.y); o.w = pack2h(b.z, b.w);
    WxL[gate][p][jw] = o;
  }

  const float bzv = bz[j], brv = br[j], bgv = bg[j];
  float hb = 0.f, hs = 0.f, kacc = 0.f, zS = 0.f;
  float az = 0.f, ar = 0.f, ag = 0.f, dtv = 0.f;
  unsigned ep = 0;

  for (int t = 0; t < kT; ++t) {
    // stage x_t (8 chains x 128) into LDS, f16-packed
    if (tid < 512) {
      const int m = tid >> 6, k2 = tid & 63;
      const float2 xv = *(const float2*)(
          x + ((size_t)(cg * MC + m) * kT + t) * kF + 2 * k2);
      xbs[m * 64 + k2] = pack2h(xv.x, xv.y);
    }
    __syncthreads();
    if (tid < 512) {   // x-part dots + dt, once per timestep
      az = bzv; ar = brv; ag = bgv;
      const uint4* xb4 = (const uint4*)xbs;
#pragma unroll
      for (int p = 0; p < 16; ++p) {
        const uint4 xv = xb4[sm * 16 + p];
        az = dot2x4(WxL[0][p][jj], xv, az);
        ar = dot2x4(WxL[1][p][jj], xv, ar);
        ag = dot2x4(WxL[2][p][jj], xv, ag);
      }
      dtv = fminf(td[(size_t)(cg * MC + sm) * kT + t], 1.0f) * 0.5f;
    }

    for (int e = 0; e < 8; ++e) {     // 2 ODE steps x 4 RK4 stages
      const int s = e & 3;
      // ---- phase A: z,r dots over h ----
      if (ep) bar_wait(ctr, WPG * ep);          // h exchange ready
      if (tid < 512) hb4[tid] = hx4[tid];       // hx -> LDS (zeros at t=0,e=0)
      __syncthreads();
      {
        float acc[MC];
#pragma unroll
        for (int m = 0; m < MC; ++m) acc[m] = 0.f;
#pragma unroll
        for (int p = 0; p < 8; ++p) {
          const uint4 w = wA[p];
#pragma unroll
          for (int m = 0; m < MC; ++m)
            acc[m] = dot2x4(w, hb4[m * 64 + ksA * 8 + p], acc[m]);
        }
#pragma unroll
        for (int m = 0; m < MC; ++m) partA[gA][ksA][m][jj] = acc[m];
      }
      __syncthreads();
      if (tid < 512) {   // reduce z,r; write rh for own neurons
        float za = az, ra = ar;
#pragma unroll
        for (int k = 0; k < 8; ++k) {
          za += partA[0][k][sm][jj];
          ra += partA[1][k][sm][jj];
        }
        zS = 1.0f / (1.0f + __expf(-za));
        const float r = 1.0f / (1.0f + __expf(-ra));
        rhx[sm * kH + j] = f2h(r * hs);
      }
      bar_arrive(ctr); ++ep;                    // rh published
      // ---- phase B: g dot over rh, RK4 update ----
      bar_wait(ctr, WPG * ep);
      if (tid < 512) hb4[tid] = rhx4[tid];      // rhx -> LDS
      __syncthreads();
      {
        float acc[4];
#pragma unroll
        for (int c = 0; c < 4; ++c) acc[c] = 0.f;
#pragma unroll
        for (int p = 0; p < 8; ++p) {
          const uint4 w = wB[p];
#pragma unroll
          for (int c = 0; c < 4; ++c)
            acc[c] = dot2x4(w, hb4[(mgB * 4 + c) * 64 + ksB * 8 + p], acc[c]);
        }
#pragma unroll
        for (int c = 0; c < 4; ++c) partB[ksB][mgB * 4 + c][jj] = acc[c];
      }
      __syncthreads();
      if (tid < 512) {
        float ga = ag;
#pragma unroll
        for (int k = 0; k < 8; ++k) ga += partB[k][sm][jj];
        const float g = tanhf(ga);
        const float kk = (1.0f - zS) * (g - hs);
        if (s == 0) kacc = kk;
        else kacc += ((s == 3) ? 1.0f : 2.0f) * kk;
        float nxt;
        if (s < 3) {
          nxt = fmaf((s == 2 ? 1.0f : 0.5f) * dtv, kk, hb);
        } else {
          hb = fmaf(dtv * (1.0f / 6.0f), kacc, hb);
          nxt = hb;
        }
        hs = nxt;
        hx[sm * kH + j] = f2h(nxt);
        if (e == 7)
          out[((size_t)(cg * MC + sm) * kT + t) * kH + j] = hb;
      }
      bar_arrive(ctr); ++ep;                    // h published
    }
  }
}

extern "C" void kernel_launch(void* const* d_in, const int* in_sizes, int n_in,
                              void* d_out, int out_size, void* d_ws, size_t ws_size,
                              hipStream_t stream) {
  const float* x  = (const float*)d_in[0];
  const float* td = (const float*)d_in[1];
  const float* Wz = (const float*)d_in[2];
  const float* bz = (const float*)d_in[3];
  const float* Wr = (const float*)d_in[4];
  const float* br = (const float*)d_in[5];
  const float* Wg = (const float*)d_in[6];
  const float* bg = (const float*)d_in[7];
  float* out = (float*)d_out;

  init_ws<<<(int)((HX_BYTES / 4 + 255) / 256), 256, 0, stream>>>(
      (unsigned*)d_ws);
  cgru_coop<<<NG * WPG, 1024, 0, stream>>>(
      x, td, Wz, bz, Wr, br, Wg, bg, d_ws, out);
}